// Round 9
// baseline (271.394 us; speedup 1.0000x reference)
//
#include <hip/hip_runtime.h>
#include <hip/hip_bf16.h>

#define D_MODEL 1024
#define N_HEADS 16
#define DK 64
#define B_SZ 4
#define T_SEQ 2048
#define M_ROWS (B_SZ * T_SEQ)   // 8192
#define QK_SCALE_LOG2 0.18033688f   // 0.125 * log2(e), folded into W_qkv Q-rows

#define XN ((size_t)M_ROWS * D_MODEL)        // 8388608
#define WQ ((size_t)3 * D_MODEL * D_MODEL)   // 3145728
#define WP ((size_t)D_MODEL * D_MODEL)       // 1048576

typedef short bf16x8 __attribute__((ext_vector_type(8)));
typedef float f32x4  __attribute__((ext_vector_type(4)));

__device__ inline unsigned short f32_to_bf16(float f) {
    union { float f; unsigned int u; } v; v.f = f;
    unsigned int r = v.u + 0x7fff + ((v.u >> 16) & 1);   // RNE
    return (unsigned short)(r >> 16);
}
__device__ inline unsigned int pack_bf16x2(float a, float b) {
    __hip_bfloat162 t = __float22bfloat162_rn(make_float2(a, b));
    union { __hip_bfloat162 v; unsigned int u; } c; c.v = t;
    return c.u;   // low 16 = a
}

// ---------------------------------------------------------------------------
// R20: single cast kernel for all three fp32->bf16 planes.
// W_qkv's first D*D elements (Q rows) get the QK scale folded in.
// ---------------------------------------------------------------------------
__global__ __launch_bounds__(256) void cast_all(
    const float* __restrict__ x, const float* __restrict__ W_qkv,
    const float* __restrict__ W_proj,
    unsigned short* __restrict__ xb, unsigned short* __restrict__ wqb,
    unsigned short* __restrict__ wpb)
{
    const size_t total = (XN + WQ + WP) / 4;
    for (size_t i4 = blockIdx.x * 256 + threadIdx.x; i4 < total;
         i4 += gridDim.x * 256) {
        const size_t i = i4 * 4;
        const float* src; unsigned short* dst; float sc = 1.0f; size_t off;
        if (i < XN) {
            src = x; dst = xb; off = i;
        } else if (i < XN + WQ) {
            off = i - XN; src = W_qkv; dst = wqb;
            if (off < (size_t)D_MODEL * D_MODEL) sc = QK_SCALE_LOG2;
        } else {
            off = i - XN - WQ; src = W_proj; dst = wpb;
        }
        float4 v = *(const float4*)(src + off);
        ushort4 h;
        h.x = f32_to_bf16(v.x * sc); h.y = f32_to_bf16(v.y * sc);
        h.z = f32_to_bf16(v.z * sc); h.w = f32_to_bf16(v.w * sc);
        *(ushort4*)(dst + off) = h;
    }
}

// ---------------------------------------------------------------------------
// bf16 NT GEMM (BK=64, XOR-swizzled LDS, gload_lds).
// R21: N-MAJOR XCD ownership — each XCD owns a contiguous slice of N-tile
// columns and iterates all M within it. Per-XCD B-slice (<=0.75MB) stays
// L2-resident for the whole sweep; A streams once per XCD (L3 serves the
// cross-XCD re-reads). R19's M-major chunks re-fetched the 6MB B panel
// (>4MB L2) once per M-row: ~384MB HBM traffic on QKV.
// FUSE_VT (R20): V-output tiles (n0 >= 2*D_MODEL) write the attn-ready
// fragment-major vt layout directly from acc registers.
// ---------------------------------------------------------------------------
template <typename OutT, bool FUSE_VT>
__global__ __launch_bounds__(256, 4) void gemm_bf16_nt(
    const unsigned short* __restrict__ A, const unsigned short* __restrict__ B,
    OutT* __restrict__ C, unsigned short* __restrict__ vt,
    int M, int N, int K)
{
    __shared__ __align__(16) unsigned short sA[128 * 64];
    __shared__ __align__(16) unsigned short sB[128 * 64];

    const int t    = threadIdx.x;
    const int wave = t >> 6;
    const int lane = t & 63;
    const int l15  = lane & 15;
    const int quad = lane >> 4;
    const int swz  = l15 & 7;

    // Bijective XCD swizzle (gridDim.x % 8 == 0), N-major within each XCD:
    // m iterates fastest -> B col-slice L2-resident, A streams (L3-amplified).
    const int cpx = gridDim.x >> 3;
    const int wg  = (blockIdx.x & 7) * cpx + (blockIdx.x >> 3);
    const int nbm = M >> 7;
    const int n0  = (wg / nbm) * 128;
    const int m0  = (wg % nbm) * 128;

    // staging: waves 0-1 -> A rows m0..m0+127, waves 2-3 -> B rows n0..n0+127
    const unsigned short* gplane = (wave < 2) ? A : B;
    unsigned short* lplane = (wave < 2) ? sA : sB;
    const int row0 = ((wave < 2) ? m0 : n0) + (wave & 1) * 64;
    unsigned short* lbase = lplane + (wave & 1) * 4096;
    const int rsub = lane >> 3;                 // 0..7 (row within 8-row strip)
    const int cg   = (lane & 7) ^ rsub;         // pre-swizzled source col-group
    const unsigned short* gbase =
        gplane + (size_t)(row0 + rsub) * K + cg * 8;

    f32x4 acc[4][4];
#pragma unroll
    for (int i = 0; i < 4; ++i)
#pragma unroll
        for (int j = 0; j < 4; ++j) acc[i][j] = (f32x4){0.f, 0.f, 0.f, 0.f};

    const int wr = (wave >> 1) * 64;
    const int wc = (wave & 1) * 64;

    for (int k0 = 0; k0 < K; k0 += 64) {
#pragma unroll
        for (int i = 0; i < 8; ++i) {
            __builtin_amdgcn_global_load_lds(
                (const __attribute__((address_space(1))) unsigned int*)
                    (gbase + k0 + (size_t)(i * 8) * K),
                (__attribute__((address_space(3))) unsigned int*)
                    (lbase + i * 512),
                16, 0, 0);
        }
        __syncthreads();

#pragma unroll
        for (int kk = 0; kk < 2; ++kk) {
            bf16x8 a[4], b[4];
            const int ch = kk * 4 + quad;
            const int co = (ch ^ swz) * 8;
#pragma unroll
            for (int f = 0; f < 4; ++f) {
                a[f] = *(const bf16x8*)&sA[(wr + f * 16 + l15) * 64 + co];
                b[f] = *(const bf16x8*)&sB[(wc + f * 16 + l15) * 64 + co];
            }
#pragma unroll
            for (int mi = 0; mi < 4; ++mi)
#pragma unroll
                for (int ni = 0; ni < 4; ++ni)
                    acc[mi][ni] = __builtin_amdgcn_mfma_f32_16x16x32_bf16(
                        a[mi], b[ni], acc[mi][ni], 0, 0, 0);
        }
        __syncthreads();
    }

    if constexpr (FUSE_VT) {
        if (n0 >= 2 * D_MODEL) {
            // V tile: write attn-ready vt fragments only (no qkvb write).
            const int bb   = m0 >> 11;            // batch (2048 rows each)
            const int tile = (m0 & 2047) >> 7;    // kv tile within batch
            const int hA   = (n0 + wc - 2 * D_MODEL) >> 6;   // head of this wave
            unsigned short* vtile =
                vt + ((size_t)((bb * N_HEADS + hA) * (T_SEQ / 128) + tile))
                     * (16 * 64 * 8);
            const int chi = (wr >> 6) * 8;
#pragma unroll
            for (int cc = 0; cc < 2; ++cc) {
                const int c   = chi + cc * 4 + quad;
                const int mi0 = 2 * cc;
#pragma unroll
                for (int ni = 0; ni < 4; ++ni) {
                    const int d = ni * 16 + l15;
                    uint4 p;
                    p.x = pack_bf16x2(acc[mi0][ni][0],     acc[mi0][ni][1]);
                    p.y = pack_bf16x2(acc[mi0][ni][2],     acc[mi0][ni][3]);
                    p.z = pack_bf16x2(acc[mi0 + 1][ni][0], acc[mi0 + 1][ni][1]);
                    p.w = pack_bf16x2(acc[mi0 + 1][ni][2], acc[mi0 + 1][ni][3]);
                    *(uint4*)(vtile + (c * 64 + d) * 8) = p;
                }
            }
            return;
        }
    }

#pragma unroll
    for (int mi = 0; mi < 4; ++mi)
#pragma unroll
        for (int r = 0; r < 4; ++r) {
            OutT* crow =
                C + (size_t)(m0 + wr + mi * 16 + quad * 4 + r) * N + n0 + wc + l15;
#pragma unroll
            for (int ni = 0; ni < 4; ++ni) {
                if constexpr (sizeof(OutT) == 2)
                    crow[ni * 16] = (OutT)f32_to_bf16(acc[mi][ni][r]);
                else
                    crow[ni * 16] = (OutT)acc[mi][ni][r];
            }
        }
}

// ---------------------------------------------------------------------------
// MFMA flash attention. R16 structure (best measured) — setprio around MFMA
// clusters, V at point of use from fragment-major global layout, K double-
// buffered via global_load_lds. R14/R15/R17/R18 all regressed: no extra V
// register buffering, no bigger Q tile.
// ---------------------------------------------------------------------------
__global__ __launch_bounds__(256, 4) void attn_mfma(
    const unsigned short* __restrict__ qkvb,   // [B,T,3D] bf16 (Q pre-scaled)
    const unsigned short* __restrict__ vt,     // [bh][tile][16][64][8] bf16
    unsigned short* __restrict__ ob)           // [B,T,D] bf16
{
    __shared__ __align__(16) unsigned short Ksw[2][128 * 64];  // [kv][dk] swizzled

    const int t    = threadIdx.x;
    const int wave = t >> 6;
    const int lane = t & 63;
    const int l15  = t & 15;
    const int quad = lane >> 4;
    const int swz  = l15 & 7;

    const int b  = blockIdx.z;
    const int h  = blockIdx.y;
    const int q0 = blockIdx.x * 128;

    // Q fragments (loop-invariant): 2 q-subtiles x 2 dk-chunks
    bf16x8 qa[2][2];
#pragma unroll
    for (int qs = 0; qs < 2; ++qs) {
        const unsigned short* qrow =
            qkvb + ((size_t)(b * T_SEQ) + q0 + wave * 32 + qs * 16 + l15)
                   * (3 * D_MODEL) + h * DK;
        qa[qs][0] = *(const bf16x8*)(qrow + quad * 8);
        qa[qs][1] = *(const bf16x8*)(qrow + 32 + quad * 8);
    }

    f32x4 O[2][4], Lacc[2];
#pragma unroll
    for (int qs = 0; qs < 2; ++qs) {
        Lacc[qs] = (f32x4){0.f, 0.f, 0.f, 0.f};
#pragma unroll
        for (int nd = 0; nd < 4; ++nd) O[qs][nd] = (f32x4){0.f, 0.f, 0.f, 0.f};
    }

    const short one_bf = (short)0x3F80;
    const bf16x8 ones8 = {one_bf, one_bf, one_bf, one_bf,
                          one_bf, one_bf, one_bf, one_bf};

    const unsigned short* kbase =
        qkvb + (size_t)(b * T_SEQ) * (3 * D_MODEL) + D_MODEL + h * DK;
    const unsigned short* vbase =
        vt + (size_t)(b * N_HEADS + h) * DK * T_SEQ;   // 16 tiles * 8192

    // K source-side swizzle (tile-invariant pieces)
    const int krl  = wave * 32 + (lane >> 3);
    const int kcol = ((lane & 7) ^ (lane >> 3)) * 8;

    // prologue: issue tile 0 K loads into buffer 0
#pragma unroll
    for (int i = 0; i < 4; ++i) {
        const int rk = krl + i * 8;
        __builtin_amdgcn_global_load_lds(
            (const __attribute__((address_space(1))) unsigned int*)
                (kbase + (size_t)rk * (3 * D_MODEL) + kcol),
            (__attribute__((address_space(3))) unsigned int*)
                (&Ksw[0][(wave * 4 + i) * 512]),
            16, 0, 0);
    }

    const int NT = T_SEQ / 128;
    for (int tile = 0; tile < NT; ++tile) {
        __syncthreads();   // drains this tile's K loads (issued one iter ago)

        if (tile + 1 < NT) {
            const int c0n = (tile + 1) * 128;
            const int nb  = (tile + 1) & 1;
#pragma unroll
            for (int i = 0; i < 4; ++i) {
                const int rk = krl + i * 8;
                __builtin_amdgcn_global_load_lds(
                    (const __attribute__((address_space(1))) unsigned int*)
                        (kbase + (size_t)(c0n + rk) * (3 * D_MODEL) + kcol),
                    (__attribute__((address_space(3))) unsigned int*)
                        (&Ksw[nb][(wave * 4 + i) * 512]),
                    16, 0, 0);
            }
        }

        const int cb = tile & 1;
        const unsigned short* vtile = vbase + (size_t)tile * (16 * 64 * 8);
        const unsigned short* vlane = vtile + quad * 512 + l15 * 8;
#pragma unroll
        for (int half = 0; half < 2; ++half) {
            f32x4 S[2][4];
#pragma unroll
            for (int qs = 0; qs < 2; ++qs)
#pragma unroll
                for (int nf = 0; nf < 4; ++nf) S[qs][nf] = (f32x4){0.f, 0.f, 0.f, 0.f};

            __builtin_amdgcn_s_setprio(1);
#pragma unroll
            for (int ks = 0; ks < 2; ++ks) {
                const int ch = ks * 4 + quad;
#pragma unroll
                for (int nf = 0; nf < 4; ++nf) {
                    const int row = half * 64 + nf * 16 + l15;   // kv
                    const bf16x8 kf =
                        *(const bf16x8*)&Ksw[cb][row * 64 + ((ch ^ swz) * 8)];
                    S[0][nf] = __builtin_amdgcn_mfma_f32_16x16x32_bf16(
                        kf, qa[0][ks], S[0][nf], 0, 0, 0);
                    S[1][nf] = __builtin_amdgcn_mfma_f32_16x16x32_bf16(
                        kf, qa[1][ks], S[1][nf], 0, 0, 0);
                }
            }
            __builtin_amdgcn_s_setprio(0);

#pragma unroll
            for (int gl = 0; gl < 2; ++gl) {
                bf16x8 pf[2];
#pragma unroll
                for (int qs = 0; qs < 2; ++qs) {
                    union { uint4 u; bf16x8 v; } cv;
                    const f32x4 s0 = S[qs][2 * gl];
                    const f32x4 s1 = S[qs][2 * gl + 1];
                    cv.u.x = pack_bf16x2(__builtin_amdgcn_exp2f(s0[0]),
                                         __builtin_amdgcn_exp2f(s0[1]));
                    cv.u.y = pack_bf16x2(__builtin_amdgcn_exp2f(s0[2]),
                                         __builtin_amdgcn_exp2f(s0[3]));
                    cv.u.z = pack_bf16x2(__builtin_amdgcn_exp2f(s1[0]),
                                         __builtin_amdgcn_exp2f(s1[1]));
                    cv.u.w = pack_bf16x2(__builtin_amdgcn_exp2f(s1[2]),
                                         __builtin_amdgcn_exp2f(s1[3]));
                    pf[qs] = cv.v;
                }
                const int g = half * 2 + gl;
                // V fragments direct from global (fragment-major layout):
                // 16 lanes of a quad-group read 256B contiguous.
                const unsigned short* vptr = vlane + (size_t)g * 2048;
                __builtin_amdgcn_s_setprio(1);
#pragma unroll
                for (int nd = 0; nd < 4; ++nd) {
                    const bf16x8 vb = *(const bf16x8*)(vptr + nd * 128);
                    O[0][nd] = __builtin_amdgcn_mfma_f32_16x16x32_bf16(
                        pf[0], vb, O[0][nd], 0, 0, 0);
                    O[1][nd] = __builtin_amdgcn_mfma_f32_16x16x32_bf16(
                        pf[1], vb, O[1][nd], 0, 0, 0);
                }
                Lacc[0] = __builtin_amdgcn_mfma_f32_16x16x32_bf16(
                    pf[0], ones8, Lacc[0], 0, 0, 0);
                Lacc[1] = __builtin_amdgcn_mfma_f32_16x16x32_bf16(
                    pf[1], ones8, Lacc[1], 0, 0, 0);
                __builtin_amdgcn_s_setprio(0);
            }
        }
    }

    // epilogue: single bf16 plane
#pragma unroll
    for (int qs = 0; qs < 2; ++qs)
#pragma unroll
        for (int r = 0; r < 4; ++r) {
            const float invl = 1.0f / Lacc[qs][r];
            const size_t rowbase =
                ((size_t)(b * T_SEQ) + q0 + wave * 32 + qs * 16 + quad * 4 + r)
                * D_MODEL + h * DK + l15;
#pragma unroll
            for (int nd = 0; nd < 4; ++nd)
                ob[rowbase + nd * 16] = f32_to_bf16(O[qs][nd][r] * invl);
        }
}

// ---------------------------------------------------------------------------
extern "C" void kernel_launch(void* const* d_in, const int* in_sizes, int n_in,
                              void* d_out, int out_size, void* d_ws, size_t ws_size,
                              hipStream_t stream)
{
    const float* x      = (const float*)d_in[0];
    const float* W_qkv  = (const float*)d_in[1];
    const float* W_proj = (const float*)d_in[2];
    float* out = (float*)d_out;

    unsigned short* xb   = (unsigned short*)d_ws;
    unsigned short* wqb  = xb + XN;
    unsigned short* wpb  = wqb + WQ;
    unsigned short* qkvb = wpb + WP;
    unsigned short* vtb  = qkvb + (size_t)M_ROWS * 3 * D_MODEL;
    unsigned short* ab   = xb;   // overlay (x plane dead after QKV GEMM)

    dim3 blk(256);
    cast_all<<<1024, blk, 0, stream>>>(x, W_qkv, W_proj, xb, wqb, wpb);

    // QKV GEMM (+fused vt build): 24 N-tiles x 64 M-tiles = 1536 blocks
    gemm_bf16_nt<unsigned short, true>
        <<<dim3((3 * D_MODEL / 128) * (M_ROWS / 128)), blk, 0, stream>>>(
        xb, wqb, qkvb, vtb, M_ROWS, 3 * D_MODEL, D_MODEL);

    attn_mfma<<<dim3(T_SEQ / 128, N_HEADS, B_SZ), blk, 0, stream>>>(
        qkvb, vtb, ab);

    // proj GEMM: 8 N-tiles x 64 M-tiles -> 512 blocks
    gemm_bf16_nt<float, false>
        <<<dim3((D_MODEL / 128) * (M_ROWS / 128)), blk, 0, stream>>>(
        ab, wpb, out, nullptr, M_ROWS, D_MODEL, D_MODEL);
}

// Round 10
// 247.221 us; speedup vs baseline: 1.0978x; 1.0978x over previous
//
#include <hip/hip_runtime.h>
#include <hip/hip_bf16.h>

#define D_MODEL 1024
#define N_HEADS 16
#define DK 64
#define B_SZ 4
#define T_SEQ 2048
#define M_ROWS (B_SZ * T_SEQ)   // 8192
#define QK_SCALE_LOG2 0.18033688f   // 0.125 * log2(e), folded into W_qkv Q-rows

#define XN ((size_t)M_ROWS * D_MODEL)        // 8388608
#define WQ ((size_t)3 * D_MODEL * D_MODEL)   // 3145728
#define WP ((size_t)D_MODEL * D_MODEL)       // 1048576

typedef short bf16x8 __attribute__((ext_vector_type(8)));
typedef float f32x4  __attribute__((ext_vector_type(4)));

__device__ inline unsigned short f32_to_bf16(float f) {
    union { float f; unsigned int u; } v; v.f = f;
    unsigned int r = v.u + 0x7fff + ((v.u >> 16) & 1);   // RNE
    return (unsigned short)(r >> 16);
}
__device__ inline unsigned int pack_bf16x2(float a, float b) {
    __hip_bfloat162 t = __float22bfloat162_rn(make_float2(a, b));
    union { __hip_bfloat162 v; unsigned int u; } c; c.v = t;
    return c.u;   // low 16 = a
}

// ---------------------------------------------------------------------------
// Single cast kernel for all three fp32->bf16 planes.
// W_qkv's first D*D elements (Q rows) get the QK scale folded in.
// ---------------------------------------------------------------------------
__global__ __launch_bounds__(256) void cast_all(
    const float* __restrict__ x, const float* __restrict__ W_qkv,
    const float* __restrict__ W_proj,
    unsigned short* __restrict__ xb, unsigned short* __restrict__ wqb,
    unsigned short* __restrict__ wpb)
{
    const size_t total = (XN + WQ + WP) / 4;
    for (size_t i4 = blockIdx.x * 256 + threadIdx.x; i4 < total;
         i4 += gridDim.x * 256) {
        const size_t i = i4 * 4;
        const float* src; unsigned short* dst; float sc = 1.0f; size_t off;
        if (i < XN) {
            src = x; dst = xb; off = i;
        } else if (i < XN + WQ) {
            off = i - XN; src = W_qkv; dst = wqb;
            if (off < (size_t)D_MODEL * D_MODEL) sc = QK_SCALE_LOG2;
        } else {
            off = i - XN - WQ; src = W_proj; dst = wpb;
        }
        float4 v = *(const float4*)(src + off);
        ushort4 h;
        h.x = f32_to_bf16(v.x * sc); h.y = f32_to_bf16(v.y * sc);
        h.z = f32_to_bf16(v.z * sc); h.w = f32_to_bf16(v.w * sc);
        *(ushort4*)(dst + off) = h;
    }
}

// ---------------------------------------------------------------------------
// bf16 NT GEMM. R22: attn-style ONE-barrier double-buffered K-loop —
// prefetch for tile t+1 issues AFTER the loop-top barrier and drains at the
// NEXT iteration's barrier, so staging loads have the whole tile-compute to
// fly (the old 2-barrier structure drained vmcnt(0) twice per K-step with
// only ~310cy of MFMA between drains -> ~490 TF). Pattern proven in
// attn_mfma (7 rounds stable). LDS 64KB -> 2 blocks/CU.
// XCD mapping reverted to R20's (R21's N-major flip regressed: L3 already
// absorbs panel re-reads; locality tweak traded away C/A locality).
// FUSE_VT: V-output tiles (n0 >= 2*D_MODEL) write the attn-ready
// fragment-major vt layout directly from acc registers.
// ---------------------------------------------------------------------------
template <typename OutT, bool FUSE_VT>
__global__ __launch_bounds__(256, 4) void gemm_bf16_nt(
    const unsigned short* __restrict__ A, const unsigned short* __restrict__ B,
    OutT* __restrict__ C, unsigned short* __restrict__ vt,
    int M, int N, int K)
{
    __shared__ __align__(16) unsigned short sA[2][128 * 64];
    __shared__ __align__(16) unsigned short sB[2][128 * 64];

    const int t    = threadIdx.x;
    const int wave = t >> 6;
    const int lane = t & 63;
    const int l15  = lane & 15;
    const int quad = lane >> 4;
    const int swz  = l15 & 7;

    // T1 bijective XCD swizzle (gridDim.x % 8 == 0), R20 mapping (N fastest).
    const int cpx = gridDim.x >> 3;
    const int wg  = (blockIdx.x & 7) * cpx + (blockIdx.x >> 3);
    const int nbx = N >> 7;
    const int n0  = (wg % nbx) * 128;
    const int m0  = (wg / nbx) * 128;

    // staging: waves 0-1 -> A rows m0..m0+127, waves 2-3 -> B rows n0..n0+127
    const unsigned short* gplane = (wave < 2) ? A : B;
    unsigned short* lplane = (wave < 2) ? sA[0] : sB[0];
    const int row0 = ((wave < 2) ? m0 : n0) + (wave & 1) * 64;
    const int loff = (wave & 1) * 4096;
    const int rsub = lane >> 3;                 // 0..7 (row within 8-row strip)
    const int cg   = (lane & 7) ^ rsub;         // pre-swizzled source col-group
    const unsigned short* gbase =
        gplane + (size_t)(row0 + rsub) * K + cg * 8;

    f32x4 acc[4][4];
#pragma unroll
    for (int i = 0; i < 4; ++i)
#pragma unroll
        for (int j = 0; j < 4; ++j) acc[i][j] = (f32x4){0.f, 0.f, 0.f, 0.f};

    const int wr = (wave >> 1) * 64;
    const int wc = (wave & 1) * 64;

    const int nk = K >> 6;
    // prologue: stage K-tile 0 into buffer 0
#pragma unroll
    for (int i = 0; i < 8; ++i) {
        __builtin_amdgcn_global_load_lds(
            (const __attribute__((address_space(1))) unsigned int*)
                (gbase + (size_t)(i * 8) * K),
            (__attribute__((address_space(3))) unsigned int*)
                (lplane + loff + i * 512),
            16, 0, 0);
    }

    for (int kt = 0; kt < nk; ++kt) {
        __syncthreads();   // drains this tile's loads (issued one iter ago)

        if (kt + 1 < nk) {
            const int k0n = (kt + 1) << 6;
            const int nb  = (kt + 1) & 1;
#pragma unroll
            for (int i = 0; i < 8; ++i) {
                __builtin_amdgcn_global_load_lds(
                    (const __attribute__((address_space(1))) unsigned int*)
                        (gbase + k0n + (size_t)(i * 8) * K),
                    (__attribute__((address_space(3))) unsigned int*)
                        (lplane + nb * 8192 + loff + i * 512),
                    16, 0, 0);
            }
        }

        const int cb = kt & 1;
#pragma unroll
        for (int kk = 0; kk < 2; ++kk) {
            bf16x8 a[4], b[4];
            const int ch = kk * 4 + quad;
            const int co = (ch ^ swz) * 8;
#pragma unroll
            for (int f = 0; f < 4; ++f) {
                a[f] = *(const bf16x8*)&sA[cb][(wr + f * 16 + l15) * 64 + co];
                b[f] = *(const bf16x8*)&sB[cb][(wc + f * 16 + l15) * 64 + co];
            }
            __builtin_amdgcn_s_setprio(1);
#pragma unroll
            for (int mi = 0; mi < 4; ++mi)
#pragma unroll
                for (int ni = 0; ni < 4; ++ni)
                    acc[mi][ni] = __builtin_amdgcn_mfma_f32_16x16x32_bf16(
                        a[mi], b[ni], acc[mi][ni], 0, 0, 0);
            __builtin_amdgcn_s_setprio(0);
        }
    }

    if constexpr (FUSE_VT) {
        if (n0 >= 2 * D_MODEL) {
            // V tile: write attn-ready vt fragments only (no qkvb write).
            const int bb   = m0 >> 11;            // batch (2048 rows each)
            const int tile = (m0 & 2047) >> 7;    // kv tile within batch
            const int hA   = (n0 + wc - 2 * D_MODEL) >> 6;   // head of this wave
            unsigned short* vtile =
                vt + ((size_t)((bb * N_HEADS + hA) * (T_SEQ / 128) + tile))
                     * (16 * 64 * 8);
            const int chi = (wr >> 6) * 8;
#pragma unroll
            for (int cc = 0; cc < 2; ++cc) {
                const int c   = chi + cc * 4 + quad;
                const int mi0 = 2 * cc;
#pragma unroll
                for (int ni = 0; ni < 4; ++ni) {
                    const int d = ni * 16 + l15;
                    uint4 p;
                    p.x = pack_bf16x2(acc[mi0][ni][0],     acc[mi0][ni][1]);
                    p.y = pack_bf16x2(acc[mi0][ni][2],     acc[mi0][ni][3]);
                    p.z = pack_bf16x2(acc[mi0 + 1][ni][0], acc[mi0 + 1][ni][1]);
                    p.w = pack_bf16x2(acc[mi0 + 1][ni][2], acc[mi0 + 1][ni][3]);
                    *(uint4*)(vtile + (c * 64 + d) * 8) = p;
                }
            }
            return;
        }
    }

#pragma unroll
    for (int mi = 0; mi < 4; ++mi)
#pragma unroll
        for (int r = 0; r < 4; ++r) {
            OutT* crow =
                C + (size_t)(m0 + wr + mi * 16 + quad * 4 + r) * N + n0 + wc + l15;
#pragma unroll
            for (int ni = 0; ni < 4; ++ni) {
                if constexpr (sizeof(OutT) == 2)
                    crow[ni * 16] = (OutT)f32_to_bf16(acc[mi][ni][r]);
                else
                    crow[ni * 16] = (OutT)acc[mi][ni][r];
            }
        }
}

// ---------------------------------------------------------------------------
// MFMA flash attention. R16 structure (best measured) — setprio around MFMA
// clusters, V at point of use from fragment-major global layout, K double-
// buffered via global_load_lds. R14/R15/R17/R18 all regressed: no extra V
// register buffering, no bigger Q tile.
// ---------------------------------------------------------------------------
__global__ __launch_bounds__(256, 4) void attn_mfma(
    const unsigned short* __restrict__ qkvb,   // [B,T,3D] bf16 (Q pre-scaled)
    const unsigned short* __restrict__ vt,     // [bh][tile][16][64][8] bf16
    unsigned short* __restrict__ ob)           // [B,T,D] bf16
{
    __shared__ __align__(16) unsigned short Ksw[2][128 * 64];  // [kv][dk] swizzled

    const int t    = threadIdx.x;
    const int wave = t >> 6;
    const int lane = t & 63;
    const int l15  = t & 15;
    const int quad = lane >> 4;
    const int swz  = l15 & 7;

    const int b  = blockIdx.z;
    const int h  = blockIdx.y;
    const int q0 = blockIdx.x * 128;

    // Q fragments (loop-invariant): 2 q-subtiles x 2 dk-chunks
    bf16x8 qa[2][2];
#pragma unroll
    for (int qs = 0; qs < 2; ++qs) {
        const unsigned short* qrow =
            qkvb + ((size_t)(b * T_SEQ) + q0 + wave * 32 + qs * 16 + l15)
                   * (3 * D_MODEL) + h * DK;
        qa[qs][0] = *(const bf16x8*)(qrow + quad * 8);
        qa[qs][1] = *(const bf16x8*)(qrow + 32 + quad * 8);
    }

    f32x4 O[2][4], Lacc[2];
#pragma unroll
    for (int qs = 0; qs < 2; ++qs) {
        Lacc[qs] = (f32x4){0.f, 0.f, 0.f, 0.f};
#pragma unroll
        for (int nd = 0; nd < 4; ++nd) O[qs][nd] = (f32x4){0.f, 0.f, 0.f, 0.f};
    }

    const short one_bf = (short)0x3F80;
    const bf16x8 ones8 = {one_bf, one_bf, one_bf, one_bf,
                          one_bf, one_bf, one_bf, one_bf};

    const unsigned short* kbase =
        qkvb + (size_t)(b * T_SEQ) * (3 * D_MODEL) + D_MODEL + h * DK;
    const unsigned short* vbase =
        vt + (size_t)(b * N_HEADS + h) * DK * T_SEQ;   // 16 tiles * 8192

    // K source-side swizzle (tile-invariant pieces)
    const int krl  = wave * 32 + (lane >> 3);
    const int kcol = ((lane & 7) ^ (lane >> 3)) * 8;

    // prologue: issue tile 0 K loads into buffer 0
#pragma unroll
    for (int i = 0; i < 4; ++i) {
        const int rk = krl + i * 8;
        __builtin_amdgcn_global_load_lds(
            (const __attribute__((address_space(1))) unsigned int*)
                (kbase + (size_t)rk * (3 * D_MODEL) + kcol),
            (__attribute__((address_space(3))) unsigned int*)
                (&Ksw[0][(wave * 4 + i) * 512]),
            16, 0, 0);
    }

    const int NT = T_SEQ / 128;
    for (int tile = 0; tile < NT; ++tile) {
        __syncthreads();   // drains this tile's K loads (issued one iter ago)

        if (tile + 1 < NT) {
            const int c0n = (tile + 1) * 128;
            const int nb  = (tile + 1) & 1;
#pragma unroll
            for (int i = 0; i < 4; ++i) {
                const int rk = krl + i * 8;
                __builtin_amdgcn_global_load_lds(
                    (const __attribute__((address_space(1))) unsigned int*)
                        (kbase + (size_t)(c0n + rk) * (3 * D_MODEL) + kcol),
                    (__attribute__((address_space(3))) unsigned int*)
                        (&Ksw[nb][(wave * 4 + i) * 512]),
                    16, 0, 0);
            }
        }

        const int cb = tile & 1;
        const unsigned short* vtile = vbase + (size_t)tile * (16 * 64 * 8);
        const unsigned short* vlane = vtile + quad * 512 + l15 * 8;
#pragma unroll
        for (int half = 0; half < 2; ++half) {
            f32x4 S[2][4];
#pragma unroll
            for (int qs = 0; qs < 2; ++qs)
#pragma unroll
                for (int nf = 0; nf < 4; ++nf) S[qs][nf] = (f32x4){0.f, 0.f, 0.f, 0.f};

            __builtin_amdgcn_s_setprio(1);
#pragma unroll
            for (int ks = 0; ks < 2; ++ks) {
                const int ch = ks * 4 + quad;
#pragma unroll
                for (int nf = 0; nf < 4; ++nf) {
                    const int row = half * 64 + nf * 16 + l15;   // kv
                    const bf16x8 kf =
                        *(const bf16x8*)&Ksw[cb][row * 64 + ((ch ^ swz) * 8)];
                    S[0][nf] = __builtin_amdgcn_mfma_f32_16x16x32_bf16(
                        kf, qa[0][ks], S[0][nf], 0, 0, 0);
                    S[1][nf] = __builtin_amdgcn_mfma_f32_16x16x32_bf16(
                        kf, qa[1][ks], S[1][nf], 0, 0, 0);
                }
            }
            __builtin_amdgcn_s_setprio(0);

#pragma unroll
            for (int gl = 0; gl < 2; ++gl) {
                bf16x8 pf[2];
#pragma unroll
                for (int qs = 0; qs < 2; ++qs) {
                    union { uint4 u; bf16x8 v; } cv;
                    const f32x4 s0 = S[qs][2 * gl];
                    const f32x4 s1 = S[qs][2 * gl + 1];
                    cv.u.x = pack_bf16x2(__builtin_amdgcn_exp2f(s0[0]),
                                         __builtin_amdgcn_exp2f(s0[1]));
                    cv.u.y = pack_bf16x2(__builtin_amdgcn_exp2f(s0[2]),
                                         __builtin_amdgcn_exp2f(s0[3]));
                    cv.u.z = pack_bf16x2(__builtin_amdgcn_exp2f(s1[0]),
                                         __builtin_amdgcn_exp2f(s1[1]));
                    cv.u.w = pack_bf16x2(__builtin_amdgcn_exp2f(s1[2]),
                                         __builtin_amdgcn_exp2f(s1[3]));
                    pf[qs] = cv.v;
                }
                const int g = half * 2 + gl;
                // V fragments direct from global (fragment-major layout):
                // 16 lanes of a quad-group read 256B contiguous.
                const unsigned short* vptr = vlane + (size_t)g * 2048;
                __builtin_amdgcn_s_setprio(1);
#pragma unroll
                for (int nd = 0; nd < 4; ++nd) {
                    const bf16x8 vb = *(const bf16x8*)(vptr + nd * 128);
                    O[0][nd] = __builtin_amdgcn_mfma_f32_16x16x32_bf16(
                        pf[0], vb, O[0][nd], 0, 0, 0);
                    O[1][nd] = __builtin_amdgcn_mfma_f32_16x16x32_bf16(
                        pf[1], vb, O[1][nd], 0, 0, 0);
                }
                Lacc[0] = __builtin_amdgcn_mfma_f32_16x16x32_bf16(
                    pf[0], ones8, Lacc[0], 0, 0, 0);
                Lacc[1] = __builtin_amdgcn_mfma_f32_16x16x32_bf16(
                    pf[1], ones8, Lacc[1], 0, 0, 0);
                __builtin_amdgcn_s_setprio(0);
            }
        }
    }

    // epilogue: single bf16 plane
#pragma unroll
    for (int qs = 0; qs < 2; ++qs)
#pragma unroll
        for (int r = 0; r < 4; ++r) {
            const float invl = 1.0f / Lacc[qs][r];
            const size_t rowbase =
                ((size_t)(b * T_SEQ) + q0 + wave * 32 + qs * 16 + quad * 4 + r)
                * D_MODEL + h * DK + l15;
#pragma unroll
            for (int nd = 0; nd < 4; ++nd)
                ob[rowbase + nd * 16] = f32_to_bf16(O[qs][nd][r] * invl);
        }
}

// ---------------------------------------------------------------------------
extern "C" void kernel_launch(void* const* d_in, const int* in_sizes, int n_in,
                              void* d_out, int out_size, void* d_ws, size_t ws_size,
                              hipStream_t stream)
{
    const float* x      = (const float*)d_in[0];
    const float* W_qkv  = (const float*)d_in[1];
    const float* W_proj = (const float*)d_in[2];
    float* out = (float*)d_out;

    unsigned short* xb   = (unsigned short*)d_ws;
    unsigned short* wqb  = xb + XN;
    unsigned short* wpb  = wqb + WQ;
    unsigned short* qkvb = wpb + WP;
    unsigned short* vtb  = qkvb + (size_t)M_ROWS * 3 * D_MODEL;
    unsigned short* ab   = xb;   // overlay (x plane dead after QKV GEMM)

    dim3 blk(256);
    cast_all<<<1024, blk, 0, stream>>>(x, W_qkv, W_proj, xb, wqb, wpb);

    // QKV GEMM (+fused vt build): 24 N-tiles x 64 M-tiles = 1536 blocks
    gemm_bf16_nt<unsigned short, true>
        <<<dim3((3 * D_MODEL / 128) * (M_ROWS / 128)), blk, 0, stream>>>(
        xb, wqb, qkvb, vtb, M_ROWS, 3 * D_MODEL, D_MODEL);

    attn_mfma<<<dim3(T_SEQ / 128, N_HEADS, B_SZ), blk, 0, stream>>>(
        qkvb, vtb, ab);

    // proj GEMM: 8 N-tiles x 64 M-tiles -> 512 blocks
    gemm_bf16_nt<float, false>
        <<<dim3((D_MODEL / 128) * (M_ROWS / 128)), blk, 0, stream>>>(
        ab, wpb, out, nullptr, M_ROWS, D_MODEL, D_MODEL);
}